// Round 6
// baseline (184.370 us; speedup 1.0000x reference)
//
#include <hip/hip_runtime.h>
#include <hip/hip_bf16.h>
#include <stdint.h>

#define B_ROWS 16384
#define NVARS 64
#define LAG 16
#define H1 64
#define H2 1024
#define KDIM (NVARS * H1)   // 4096

typedef __attribute__((ext_vector_type(8))) short short8;
typedef __attribute__((ext_vector_type(4))) short short4v;
typedef __attribute__((ext_vector_type(4))) float f32x4;

typedef __attribute__((address_space(3))) uint8_t lds_u8;
typedef const __attribute__((address_space(1))) uint8_t glob_u8;

__device__ __forceinline__ void gload_lds16(const void* g, void* l) {
    __builtin_amdgcn_global_load_lds((glob_u8*)g, (lds_u8*)l, 16, 0, 0);
}

__device__ __forceinline__ short f2bf_s(float x) {
    __hip_bfloat16 h = __float2bfloat16(x);
    return *(short*)&h;
}
__device__ __forceinline__ float bf_s2f(short s) {
    __hip_bfloat16 h = *(__hip_bfloat16*)&s;
    return __bfloat162float(h);
}

// ---------------------------------------------------------------------------
// Fused pre-kernel: one dispatch, three independent jobs by blockIdx range:
//   [0,1024)      : W3 [4096][1024] f32 -> W3T [1024][4096] bf16
//   [1024,1088)   : out[i] = b4[0]
//   [1088,9280)   : per-variable 2-layer subnet (split-bf16 MFMA, r2-validated
//                   math) with INLINE W1/W2 -> hi/lo conversion (prep kernel
//                   eliminated; each block converts its var's 20 KB of f32).
// ---------------------------------------------------------------------------
__global__ __launch_bounds__(256) void fused_pre_kernel(
    const float* __restrict__ inputs, const float* __restrict__ W1,
    const float* __restrict__ b1g, const float* __restrict__ W2,
    const float* __restrict__ b2g, const float* __restrict__ impg,
    const float* __restrict__ w3, const float* __restrict__ b4,
    __hip_bfloat16* __restrict__ w3t, __hip_bfloat16* __restrict__ agg,
    float* __restrict__ out) {
    __shared__ __align__(16) char smem[53248];
    const int bid = blockIdx.x;
    const int t = threadIdx.x;

    if (bid < 1024) {
        // ---- W3 transpose + bf16 convert ----
        float (*tile)[65] = (float (*)[65])smem;
        const int k0 = (bid >> 4) * 64;
        const int n0 = (bid & 15) * 64;
        const int c = t & 63, r0 = t >> 6;
#pragma unroll
        for (int i = 0; i < 16; i++) {
            int r = r0 + i * 4;
            tile[r][c] = w3[(size_t)(k0 + r) * H2 + n0 + c];
        }
        __syncthreads();
#pragma unroll
        for (int i = 0; i < 16; i++) {
            int nr = r0 + i * 4;
            w3t[(size_t)(n0 + nr) * KDIM + k0 + c] = __float2bfloat16(tile[c][nr]);
        }
        return;
    }
    if (bid < 1088) {
        out[(bid - 1024) * 256 + t] = b4[0];
        return;
    }

    // ---- subnets ----
    const int sbid = bid - 1088;
    const int v = sbid >> 7;
    const int b0 = (sbid & 127) * 128;
    const int lane = t & 63, wv = t >> 6;
    const int l15 = lane & 15, g = lane >> 4;

    short* xsS   = (short*)smem;               // [128][40]
    short* w1bhS = (short*)(smem + 10240);     // [64][40]
    short* w1blS = (short*)(smem + 15360);
    short* Hs    = (short*)smem;               // [128][136] (post-L1)
    short* w2bhS = (short*)(smem + 34816);     // [64][72]
    short* w2blS = (short*)(smem + 44032);

    // inline conversion: W1 [16][64] -> w1b [col][40] (hi duplicated k/k+16)
    for (int idx = t; idx < LAG * H1; idx += 256) {
        int l = idx >> 6, col = idx & 63;
        float w = W1[(size_t)v * (LAG * H1) + idx];
        short hi = f2bf_s(w), lo = f2bf_s(w - bf_s2f(hi));
        w1bhS[col * 40 + l] = hi;
        w1bhS[col * 40 + 16 + l] = hi;
        w1blS[col * 40 + l] = lo;
        w1blS[col * 40 + 16 + l] = 0;
    }
    // W2 [64][64] -> w2b [col][72]
    for (int idx = t; idx < H1 * H1; idx += 256) {
        int k = idx >> 6, col = idx & 63;
        float w = W2[(size_t)v * (H1 * H1) + idx];
        short hi = f2bf_s(w), lo = f2bf_s(w - bf_s2f(hi));
        w2bhS[col * 72 + k] = hi;
        w2blS[col * 72 + k] = lo;
    }
    // x staging, split hi/lo: xs[row][k<16]=hi, [16..31]=lo
#pragma unroll
    for (int i = 0; i < 2; i++) {
        int idx = t + i * 256;
        int row = idx >> 2, seg = idx & 3;
        float4 x4 = *(const float4*)(inputs + (size_t)(b0 + row) * (NVARS * LAG) + v * LAG + seg * 4);
        const float* xp = (const float*)&x4;
        short4v hv, lv;
#pragma unroll
        for (int j = 0; j < 4; j++) {
            short hi = f2bf_s(xp[j]);
            hv[j] = hi;
            lv[j] = f2bf_s(xp[j] - bf_s2f(hi));
        }
        *(short4v*)&xsS[row * 40 + seg * 4] = hv;
        *(short4v*)&xsS[row * 40 + 16 + seg * 4] = lv;
    }
    __syncthreads();

    // layer 1
    short8 a1[2], b1hF[4], b1lF[4];
#pragma unroll
    for (int mt = 0; mt < 2; mt++)
        a1[mt] = *(const short8*)&xsS[(wv * 32 + mt * 16 + l15) * 40 + g * 8];
#pragma unroll
    for (int nt = 0; nt < 4; nt++) {
        b1hF[nt] = *(const short8*)&w1bhS[(nt * 16 + l15) * 40 + g * 8];
        b1lF[nt] = *(const short8*)&w1blS[(nt * 16 + l15) * 40 + g * 8];
    }
    f32x4 acc1[2][4];
#pragma unroll
    for (int mt = 0; mt < 2; mt++)
#pragma unroll
        for (int nt = 0; nt < 4; nt++) {
            acc1[mt][nt] = (f32x4){0.f, 0.f, 0.f, 0.f};
            acc1[mt][nt] = __builtin_amdgcn_mfma_f32_16x16x32_bf16(a1[mt], b1hF[nt], acc1[mt][nt], 0, 0, 0);
            acc1[mt][nt] = __builtin_amdgcn_mfma_f32_16x16x32_bf16(a1[mt], b1lF[nt], acc1[mt][nt], 0, 0, 0);
        }
    __syncthreads();

    // relu + hi/lo split -> H [128][136]: cols 0-63 hi, 64-127 lo
#pragma unroll
    for (int mt = 0; mt < 2; mt++)
#pragma unroll
        for (int nt = 0; nt < 4; nt++) {
            int col = nt * 16 + l15;
            float bias = b1g[v * H1 + col];
#pragma unroll
            for (int r = 0; r < 4; r++) {
                float h = fmaxf(acc1[mt][nt][r] + bias, 0.f);
                short hi = f2bf_s(h);
                short lo = f2bf_s(h - bf_s2f(hi));
                int row = wv * 32 + mt * 16 + g * 4 + r;
                Hs[row * 136 + col] = hi;
                Hs[row * 136 + 64 + col] = lo;
            }
        }
    __syncthreads();

    // layer 2
    short8 a2[2][4], b2hF[4][2], b2lF[4][2];
#pragma unroll
    for (int mt = 0; mt < 2; mt++)
#pragma unroll
        for (int c = 0; c < 4; c++)
            a2[mt][c] = *(const short8*)&Hs[(wv * 32 + mt * 16 + l15) * 136 + c * 32 + g * 8];
#pragma unroll
    for (int nt = 0; nt < 4; nt++)
#pragma unroll
        for (int kc = 0; kc < 2; kc++) {
            b2hF[nt][kc] = *(const short8*)&w2bhS[(nt * 16 + l15) * 72 + kc * 32 + g * 8];
            b2lF[nt][kc] = *(const short8*)&w2blS[(nt * 16 + l15) * 72 + kc * 32 + g * 8];
        }
    f32x4 acc2[2][4];
#pragma unroll
    for (int mt = 0; mt < 2; mt++)
#pragma unroll
        for (int nt = 0; nt < 4; nt++) {
            f32x4 a = (f32x4){0.f, 0.f, 0.f, 0.f};
            a = __builtin_amdgcn_mfma_f32_16x16x32_bf16(a2[mt][0], b2hF[nt][0], a, 0, 0, 0);
            a = __builtin_amdgcn_mfma_f32_16x16x32_bf16(a2[mt][1], b2hF[nt][1], a, 0, 0, 0);
            a = __builtin_amdgcn_mfma_f32_16x16x32_bf16(a2[mt][2], b2hF[nt][0], a, 0, 0, 0);
            a = __builtin_amdgcn_mfma_f32_16x16x32_bf16(a2[mt][3], b2hF[nt][1], a, 0, 0, 0);
            a = __builtin_amdgcn_mfma_f32_16x16x32_bf16(a2[mt][0], b2lF[nt][0], a, 0, 0, 0);
            a = __builtin_amdgcn_mfma_f32_16x16x32_bf16(a2[mt][1], b2lF[nt][1], a, 0, 0, 0);
            acc2[mt][nt] = a;
        }

    const float impv = impg[v];
#pragma unroll
    for (int mt = 0; mt < 2; mt++)
#pragma unroll
        for (int nt = 0; nt < 4; nt++) {
            int col = nt * 16 + l15;
            float bias = b2g[v * H1 + col];
#pragma unroll
            for (int r = 0; r < 4; r++) {
                float o = fmaxf(acc2[mt][nt][r] + bias, 0.f) * impv;
                int row = b0 + wv * 32 + mt * 16 + g * 4 + r;
                agg[(size_t)row * KDIM + v * H1 + col] = __float2bfloat16(o);
            }
        }
}

// ---------------------------------------------------------------------------
// Kernel C: relu(agg @ W3 + b3) . W4 -> atomicAdd into out.
// 256x256 tile, BK=32, 8 waves (2Mx4N), 512 thr, 4 LDS buffer pairs (128 KB),
// stage tile tt+3 during tile tt. NEW: 1 barrier + 1 vmcnt per K-tile (4-buf
// slack makes the mid-phase barrier & forced lgkmcnt(0) unnecessary); the
// compiler's own fine-grained lgkmcnt orders ds_read->MFMA; per-tile asm
// memory clobber stops cross-tile hoisting of ds_reads.
// ---------------------------------------------------------------------------
#define NT 128   // K-tiles of 32

__global__ __launch_bounds__(512, 2) void gemm3_kernel(
    const __hip_bfloat16* __restrict__ agg,   // [16384][4096]
    const __hip_bfloat16* __restrict__ w3t,   // [1024][4096]
    const float* __restrict__ b3, const float* __restrict__ W4,
    float* __restrict__ out) {
    // XCD swizzle (T1): XCD x gets bids [32x,32x+32) = 8 row-panels x 4 cols.
    const int bid = ((blockIdx.x & 7) << 5) + (blockIdx.x >> 3);
    const int brow = (bid >> 2) * 256;
    const int bcol = (bid & 3) * 256;
    const int t = threadIdx.x;
    const int lane = t & 63;
    const int wid = t >> 6;                   // 8 waves
    const int wm = wid >> 2, wn = wid & 3;    // 2 x 4, wave tile 128x64
    const int l15 = lane & 15, g = lane >> 4;

    // LDS: buffer pair p (p=0..3) at p*32768: A 16 KB @ +0, B 16 KB @ +16384
    __shared__ __align__(16) char smem[131072];

    // staging: chunk c -> dest byte c*16 (linear); source col pre-swizzled
    const int c0 = t, c1 = t + 512;
    const int r0 = c0 >> 2, r1 = c1 >> 2;
    const int col0 = ((c0 & 3) * 8) ^ ((r0 & 8) ? 16 : 0);
    const int col1 = ((c1 & 3) * 8) ^ ((r1 & 8) ? 16 : 0);
    const __hip_bfloat16* aS0 = agg + (size_t)(brow + r0) * KDIM + col0;
    const __hip_bfloat16* aS1 = agg + (size_t)(brow + r1) * KDIM + col1;
    const __hip_bfloat16* bS0 = w3t + (size_t)(bcol + r0) * KDIM + col0;
    const __hip_bfloat16* bS1 = w3t + (size_t)(bcol + r1) * KDIM + col1;

#define STAGE_A(p, kt) do { \
        gload_lds16(aS0 + (kt) * 32, smem + (p) * 32768 + c0 * 16); \
        gload_lds16(aS1 + (kt) * 32, smem + (p) * 32768 + c1 * 16); } while (0)
#define STAGE_B(p, kt) do { \
        gload_lds16(bS0 + (kt) * 32, smem + (p) * 32768 + 16384 + c0 * 16); \
        gload_lds16(bS1 + (kt) * 32, smem + (p) * 32768 + 16384 + c1 * 16); } while (0)

    // swizzled fragment reads (row&8 == l15&8 for all m/n)
    const int coff = (g * 16) ^ ((l15 & 8) ? 32 : 0);
    const int aBase = (wm * 128 + l15) * 64 + coff;
    const int bBase = 16384 + (wn * 64 + l15) * 64 + coff;

#define LDA(i, p) fa[i] = *(const short8*)(smem + (p) * 32768 + aBase + (i) * 1024)
#define LDB(i, p) fb[i] = *(const short8*)(smem + (p) * 32768 + bBase + (i) * 1024)

    short8 fa[8], fb[4];
    f32x4 acc[8][4];
#pragma unroll
    for (int m = 0; m < 8; m++)
#pragma unroll
        for (int n = 0; n < 4; n++) acc[m][n] = (f32x4){0.f, 0.f, 0.f, 0.f};

    // prologue: stage tiles 0,1,2; vmcnt(8) -> tile0 landed; barrier
    STAGE_A(0, 0); STAGE_B(0, 0);
    STAGE_A(1, 1); STAGE_B(1, 1);
    STAGE_A(2, 2); STAGE_B(2, 2);
    asm volatile("s_waitcnt vmcnt(8)" ::: "memory");
    __builtin_amdgcn_s_barrier();
    __builtin_amdgcn_sched_barrier(0);

    // Tile tt: PH_A {8 ds_reads, stage A(tt+3), 16 MFMA}, PH_B {4 ds_reads,
    // stage B(tt+3), 16 MFMA, vmcnt (tt+1 landed), barrier}. Compiler inserts
    // minimal lgkmcnt splits for ds_read->MFMA; no forced drains.
#define PH_A(p, DOSTAGE, kt3) do { \
        LDA(0, p); LDA(1, p); LDA(2, p); LDA(3, p); \
        LDB(0, p); LDB(1, p); LDB(2, p); LDB(3, p); \
        if (DOSTAGE) STAGE_A((kt3) & 3, kt3); \
        __builtin_amdgcn_s_setprio(1); \
        _Pragma("unroll") \
        for (int mm = 0; mm < 4; mm++) \
            _Pragma("unroll") \
            for (int nn = 0; nn < 4; nn++) \
                acc[mm][nn] = __builtin_amdgcn_mfma_f32_16x16x32_bf16( \
                    fa[mm], fb[nn], acc[mm][nn], 0, 0, 0); \
        __builtin_amdgcn_s_setprio(0); } while (0)

#define PH_B(p, DOSTAGE, kt3, VMSTR) do { \
        LDA(4, p); LDA(5, p); LDA(6, p); LDA(7, p); \
        if (DOSTAGE) STAGE_B((kt3) & 3, kt3); \
        __builtin_amdgcn_s_setprio(1); \
        _Pragma("unroll") \
        for (int mm = 0; mm < 4; mm++) \
            _Pragma("unroll") \
            for (int nn = 0; nn < 4; nn++) \
                acc[4 + mm][nn] = __builtin_amdgcn_mfma_f32_16x16x32_bf16( \
                    fa[4 + mm], fb[nn], acc[4 + mm][nn], 0, 0, 0); \
        __builtin_amdgcn_s_setprio(0); \
        asm volatile(VMSTR ::: "memory"); \
        __builtin_amdgcn_s_barrier(); \
        __builtin_amdgcn_sched_barrier(0); } while (0)

    // main loop: tt = 0..123 (unroll 4 -> p compile-time)
#pragma unroll 4
    for (int tt = 0; tt < NT - 4; ++tt) {
        const int p = tt & 3;
        PH_A(p, 1, tt + 3);
        PH_B(p, 1, tt + 3, "s_waitcnt vmcnt(8)");
    }
    // peeled tail: 124 (stages 127), 125, 126, 127
    PH_A(0, 1, 127); PH_B(0, 1, 127, "s_waitcnt vmcnt(8)");
    PH_A(1, 0, 0);   PH_B(1, 0, 0, "s_waitcnt vmcnt(4)");
    PH_A(2, 0, 0);   PH_B(2, 0, 0, "s_waitcnt vmcnt(0)");
    PH_A(3, 0, 0);   PH_B(3, 0, 0, "s_waitcnt vmcnt(0)");

    // epilogue: bias+relu, dot W4, 16-lane reduce, atomicAdd per row
    float bias[4], w4v[4];
#pragma unroll
    for (int n = 0; n < 4; n++) {
        int col = bcol + wn * 64 + n * 16 + l15;
        bias[n] = b3[col];
        w4v[n] = W4[col];
    }
#pragma unroll
    for (int m = 0; m < 8; m++) {
        float pr0 = 0.f, pr1 = 0.f, pr2 = 0.f, pr3 = 0.f;
#pragma unroll
        for (int n = 0; n < 4; n++) {
            pr0 += fmaxf(acc[m][n][0] + bias[n], 0.f) * w4v[n];
            pr1 += fmaxf(acc[m][n][1] + bias[n], 0.f) * w4v[n];
            pr2 += fmaxf(acc[m][n][2] + bias[n], 0.f) * w4v[n];
            pr3 += fmaxf(acc[m][n][3] + bias[n], 0.f) * w4v[n];
        }
#pragma unroll
        for (int mask = 1; mask < 16; mask <<= 1) {
            pr0 += __shfl_xor(pr0, mask, 64);
            pr1 += __shfl_xor(pr1, mask, 64);
            pr2 += __shfl_xor(pr2, mask, 64);
            pr3 += __shfl_xor(pr3, mask, 64);
        }
        if (l15 == 0) {
            int row = brow + wm * 128 + m * 16 + g * 4;
            atomicAdd(&out[row + 0], pr0);
            atomicAdd(&out[row + 1], pr1);
            atomicAdd(&out[row + 2], pr2);
            atomicAdd(&out[row + 3], pr3);
        }
    }
}

// ---------------------------------------------------------------------------
extern "C" void kernel_launch(void* const* d_in, const int* in_sizes, int n_in,
                              void* d_out, int out_size, void* d_ws, size_t ws_size,
                              hipStream_t stream) {
    const float* inputs = (const float*)d_in[0];
    const float* W1 = (const float*)d_in[1];
    const float* b1 = (const float*)d_in[2];
    const float* W2 = (const float*)d_in[3];
    const float* b2 = (const float*)d_in[4];
    const float* imp = (const float*)d_in[5];
    const float* W3 = (const float*)d_in[6];
    const float* b3 = (const float*)d_in[7];
    const float* W4 = (const float*)d_in[8];
    const float* b4 = (const float*)d_in[9];
    float* out = (float*)d_out;

    char* ws = (char*)d_ws;
    const size_t agg_bytes = (size_t)B_ROWS * KDIM * 2;   // 134 MB
    __hip_bfloat16* agg = (__hip_bfloat16*)ws;
    __hip_bfloat16* w3t = (__hip_bfloat16*)(ws + agg_bytes);   // 8.4 MB

    // fused pre: [0,1024) w3t transpose, [1024,1088) out init, rest subnets
    hipLaunchKernelGGL(fused_pre_kernel, dim3(1088 + NVARS * (B_ROWS / 128)), dim3(256), 0, stream,
                       inputs, W1, b1, W2, b2, imp, W3, b4, w3t, agg, out);
    hipLaunchKernelGGL(gemm3_kernel, dim3((B_ROWS / 256) * (H2 / 256)), dim3(512), 0, stream,
                       agg, w3t, b3, W4, out);
}

// Round 7
// 179.241 us; speedup vs baseline: 1.0286x; 1.0286x over previous
//
#include <hip/hip_runtime.h>
#include <hip/hip_bf16.h>
#include <stdint.h>

#define B_ROWS 16384
#define NVARS 64
#define LAG 16
#define H1 64
#define H2 1024
#define KDIM (NVARS * H1)   // 4096

typedef __attribute__((ext_vector_type(8))) short short8;
typedef __attribute__((ext_vector_type(4))) short short4v;
typedef __attribute__((ext_vector_type(4))) float f32x4;

typedef __attribute__((address_space(3))) uint8_t lds_u8;
typedef const __attribute__((address_space(1))) uint8_t glob_u8;

__device__ __forceinline__ void gload_lds16(const void* g, void* l) {
    __builtin_amdgcn_global_load_lds((glob_u8*)g, (lds_u8*)l, 16, 0, 0);
}

__device__ __forceinline__ short f2bf_s(float x) {
    __hip_bfloat16 h = __float2bfloat16(x);
    return *(short*)&h;
}
__device__ __forceinline__ float bf_s2f(short s) {
    __hip_bfloat16 h = *(__hip_bfloat16*)&s;
    return __bfloat162float(h);
}

// ---------------------------------------------------------------------------
// Kernel 1 (run-once misc, one dispatch):
//   [0,1024)    : W3 [4096][1024] f32 -> W3T [1024][4096] bf16 (LDS transpose)
//   [1024,1088) : out[i] = b4[0]
//   [1088,1152) : per-var W1/W2 -> hi/lo B-operand tiles (GLOBAL writes, no
//                 LDS -> no bank conflicts; runs ONCE, unlike r6's per-block
//                 inline conversion which cost 60 us + 1.4e7 conflicts)
// ---------------------------------------------------------------------------
__global__ __launch_bounds__(256) void misc_pre_kernel(
    const float* __restrict__ w3, const float* __restrict__ b4,
    const float* __restrict__ W1, const float* __restrict__ W2,
    __hip_bfloat16* __restrict__ w3t, float* __restrict__ out,
    short* __restrict__ w1bh, short* __restrict__ w1bl,
    short* __restrict__ w2bh, short* __restrict__ w2bl) {
    __shared__ float tile[64][65];
    const int bid = blockIdx.x;
    const int t = threadIdx.x;

    if (bid < 1024) {
        const int k0 = (bid >> 4) * 64;
        const int n0 = (bid & 15) * 64;
        const int c = t & 63, r0 = t >> 6;
#pragma unroll
        for (int i = 0; i < 16; i++) {
            int r = r0 + i * 4;
            tile[r][c] = w3[(size_t)(k0 + r) * H2 + n0 + c];
        }
        __syncthreads();
#pragma unroll
        for (int i = 0; i < 16; i++) {
            int nr = r0 + i * 4;
            w3t[(size_t)(n0 + nr) * KDIM + k0 + c] = __float2bfloat16(tile[c][nr]);
        }
        return;
    }
    if (bid < 1088) {
        out[(bid - 1024) * 256 + t] = b4[0];
        return;
    }

    const int v = bid - 1088;
    for (int idx = t; idx < 64 * 32; idx += 256) {
        int col = idx >> 5, k = idx & 31;
        float wv = W1[((size_t)v * LAG + (k & 15)) * H1 + col];
        short hi = f2bf_s(wv);
        w1bh[((size_t)v * 64 + col) * 40 + k] = hi;
        w1bl[((size_t)v * 64 + col) * 40 + k] = (k < 16) ? f2bf_s(wv - bf_s2f(hi)) : (short)0;
    }
    for (int idx = t; idx < 64 * 64; idx += 256) {
        int col = idx >> 6, k = idx & 63;
        float wv = W2[((size_t)v * H1 + k) * H1 + col];
        short hi = f2bf_s(wv);
        w2bh[((size_t)v * 64 + col) * 72 + k] = hi;
        w2bl[((size_t)v * 64 + col) * 72 + k] = f2bf_s(wv - bf_s2f(hi));
    }
}

// ---------------------------------------------------------------------------
// Kernel 2: per-variable 2-layer subnet via split-bf16 MFMA (r2/r5 validated).
// ---------------------------------------------------------------------------
__global__ __launch_bounds__(256) void subnets_mfma_kernel(
    const float* __restrict__ inputs, const float* __restrict__ b1g,
    const float* __restrict__ b2g, const float* __restrict__ impg,
    const short* __restrict__ w1bh_g, const short* __restrict__ w1bl_g,
    const short* __restrict__ w2bh_g, const short* __restrict__ w2bl_g,
    __hip_bfloat16* __restrict__ agg) {
    const int v = blockIdx.x >> 7;
    const int b0 = (blockIdx.x & 127) * 128;
    const int t = threadIdx.x;
    const int lane = t & 63, wv = t >> 6;
    const int l15 = lane & 15, g = lane >> 4;

    __shared__ __align__(16) char smem[53248];
    short* xsS   = (short*)smem;
    short* w1bhS = (short*)(smem + 10240);
    short* w1blS = (short*)(smem + 15360);
    short* Hs    = (short*)smem;
    short* w2bhS = (short*)(smem + 34816);
    short* w2blS = (short*)(smem + 44032);

    for (int c = t; c < 320; c += 256) {
        gload_lds16(w1bh_g + (size_t)v * 2560 + c * 8, (char*)w1bhS + c * 16);
        gload_lds16(w1bl_g + (size_t)v * 2560 + c * 8, (char*)w1blS + c * 16);
    }
    for (int c = t; c < 576; c += 256) {
        gload_lds16(w2bh_g + (size_t)v * 4608 + c * 8, (char*)w2bhS + c * 16);
        gload_lds16(w2bl_g + (size_t)v * 4608 + c * 8, (char*)w2blS + c * 16);
    }
#pragma unroll
    for (int i = 0; i < 2; i++) {
        int idx = t + i * 256;
        int row = idx >> 2, seg = idx & 3;
        float4 x4 = *(const float4*)(inputs + (size_t)(b0 + row) * (NVARS * LAG) + v * LAG + seg * 4);
        const float* xp = (const float*)&x4;
        short4v hv, lv;
#pragma unroll
        for (int j = 0; j < 4; j++) {
            short hi = f2bf_s(xp[j]);
            hv[j] = hi;
            lv[j] = f2bf_s(xp[j] - bf_s2f(hi));
        }
        *(short4v*)&xsS[row * 40 + seg * 4] = hv;
        *(short4v*)&xsS[row * 40 + 16 + seg * 4] = lv;
    }
    __syncthreads();

    short8 a1[2], b1hF[4], b1lF[4];
#pragma unroll
    for (int mt = 0; mt < 2; mt++)
        a1[mt] = *(const short8*)&xsS[(wv * 32 + mt * 16 + l15) * 40 + g * 8];
#pragma unroll
    for (int nt = 0; nt < 4; nt++) {
        b1hF[nt] = *(const short8*)&w1bhS[(nt * 16 + l15) * 40 + g * 8];
        b1lF[nt] = *(const short8*)&w1blS[(nt * 16 + l15) * 40 + g * 8];
    }
    f32x4 acc1[2][4];
#pragma unroll
    for (int mt = 0; mt < 2; mt++)
#pragma unroll
        for (int nt = 0; nt < 4; nt++) {
            acc1[mt][nt] = (f32x4){0.f, 0.f, 0.f, 0.f};
            acc1[mt][nt] = __builtin_amdgcn_mfma_f32_16x16x32_bf16(a1[mt], b1hF[nt], acc1[mt][nt], 0, 0, 0);
            acc1[mt][nt] = __builtin_amdgcn_mfma_f32_16x16x32_bf16(a1[mt], b1lF[nt], acc1[mt][nt], 0, 0, 0);
        }
    __syncthreads();

#pragma unroll
    for (int mt = 0; mt < 2; mt++)
#pragma unroll
        for (int nt = 0; nt < 4; nt++) {
            int col = nt * 16 + l15;
            float bias = b1g[v * H1 + col];
#pragma unroll
            for (int r = 0; r < 4; r++) {
                float h = fmaxf(acc1[mt][nt][r] + bias, 0.f);
                short hi = f2bf_s(h);
                short lo = f2bf_s(h - bf_s2f(hi));
                int row = wv * 32 + mt * 16 + g * 4 + r;
                Hs[row * 136 + col] = hi;
                Hs[row * 136 + 64 + col] = lo;
            }
        }
    __syncthreads();

    short8 a2[2][4], b2hF[4][2], b2lF[4][2];
#pragma unroll
    for (int mt = 0; mt < 2; mt++)
#pragma unroll
        for (int c = 0; c < 4; c++)
            a2[mt][c] = *(const short8*)&Hs[(wv * 32 + mt * 16 + l15) * 136 + c * 32 + g * 8];
#pragma unroll
    for (int nt = 0; nt < 4; nt++)
#pragma unroll
        for (int kc = 0; kc < 2; kc++) {
            b2hF[nt][kc] = *(const short8*)&w2bhS[(nt * 16 + l15) * 72 + kc * 32 + g * 8];
            b2lF[nt][kc] = *(const short8*)&w2blS[(nt * 16 + l15) * 72 + kc * 32 + g * 8];
        }
    f32x4 acc2[2][4];
#pragma unroll
    for (int mt = 0; mt < 2; mt++)
#pragma unroll
        for (int nt = 0; nt < 4; nt++) {
            f32x4 a = (f32x4){0.f, 0.f, 0.f, 0.f};
            a = __builtin_amdgcn_mfma_f32_16x16x32_bf16(a2[mt][0], b2hF[nt][0], a, 0, 0, 0);
            a = __builtin_amdgcn_mfma_f32_16x16x32_bf16(a2[mt][1], b2hF[nt][1], a, 0, 0, 0);
            a = __builtin_amdgcn_mfma_f32_16x16x32_bf16(a2[mt][2], b2hF[nt][0], a, 0, 0, 0);
            a = __builtin_amdgcn_mfma_f32_16x16x32_bf16(a2[mt][3], b2hF[nt][1], a, 0, 0, 0);
            a = __builtin_amdgcn_mfma_f32_16x16x32_bf16(a2[mt][0], b2lF[nt][0], a, 0, 0, 0);
            a = __builtin_amdgcn_mfma_f32_16x16x32_bf16(a2[mt][1], b2lF[nt][1], a, 0, 0, 0);
            acc2[mt][nt] = a;
        }

    const float impv = impg[v];
#pragma unroll
    for (int mt = 0; mt < 2; mt++)
#pragma unroll
        for (int nt = 0; nt < 4; nt++) {
            int col = nt * 16 + l15;
            float bias = b2g[v * H1 + col];
#pragma unroll
            for (int r = 0; r < 4; r++) {
                float o = fmaxf(acc2[mt][nt][r] + bias, 0.f) * impv;
                int row = b0 + wv * 32 + mt * 16 + g * 4 + r;
                agg[(size_t)row * KDIM + v * H1 + col] = __float2bfloat16(o);
            }
        }
}

// ---------------------------------------------------------------------------
// Kernel 3: relu(agg @ W3 + b3) . W4 -> atomicAdd into out.
// r6-validated single-barrier schedule: 256x256 tile, BK=32, 8 waves, 4 LDS
// buffer pairs, stage tt+3 during tt, 1 barrier + 1 vmcnt(8) per K-tile.
// ---------------------------------------------------------------------------
#define NT 128   // K-tiles of 32

__global__ __launch_bounds__(512, 2) void gemm3_kernel(
    const __hip_bfloat16* __restrict__ agg,   // [16384][4096]
    const __hip_bfloat16* __restrict__ w3t,   // [1024][4096]
    const float* __restrict__ b3, const float* __restrict__ W4,
    float* __restrict__ out) {
    const int bid = ((blockIdx.x & 7) << 5) + (blockIdx.x >> 3);
    const int brow = (bid >> 2) * 256;
    const int bcol = (bid & 3) * 256;
    const int t = threadIdx.x;
    const int lane = t & 63;
    const int wid = t >> 6;
    const int wm = wid >> 2, wn = wid & 3;
    const int l15 = lane & 15, g = lane >> 4;

    __shared__ __align__(16) char smem[131072];

    const int c0 = t, c1 = t + 512;
    const int r0 = c0 >> 2, r1 = c1 >> 2;
    const int col0 = ((c0 & 3) * 8) ^ ((r0 & 8) ? 16 : 0);
    const int col1 = ((c1 & 3) * 8) ^ ((r1 & 8) ? 16 : 0);
    const __hip_bfloat16* aS0 = agg + (size_t)(brow + r0) * KDIM + col0;
    const __hip_bfloat16* aS1 = agg + (size_t)(brow + r1) * KDIM + col1;
    const __hip_bfloat16* bS0 = w3t + (size_t)(bcol + r0) * KDIM + col0;
    const __hip_bfloat16* bS1 = w3t + (size_t)(bcol + r1) * KDIM + col1;

#define STAGE_A(p, kt) do { \
        gload_lds16(aS0 + (kt) * 32, smem + (p) * 32768 + c0 * 16); \
        gload_lds16(aS1 + (kt) * 32, smem + (p) * 32768 + c1 * 16); } while (0)
#define STAGE_B(p, kt) do { \
        gload_lds16(bS0 + (kt) * 32, smem + (p) * 32768 + 16384 + c0 * 16); \
        gload_lds16(bS1 + (kt) * 32, smem + (p) * 32768 + 16384 + c1 * 16); } while (0)

    const int coff = (g * 16) ^ ((l15 & 8) ? 32 : 0);
    const int aBase = (wm * 128 + l15) * 64 + coff;
    const int bBase = 16384 + (wn * 64 + l15) * 64 + coff;

#define LDA(i, p) fa[i] = *(const short8*)(smem + (p) * 32768 + aBase + (i) * 1024)
#define LDB(i, p) fb[i] = *(const short8*)(smem + (p) * 32768 + bBase + (i) * 1024)

    short8 fa[8], fb[4];
    f32x4 acc[8][4];
#pragma unroll
    for (int m = 0; m < 8; m++)
#pragma unroll
        for (int n = 0; n < 4; n++) acc[m][n] = (f32x4){0.f, 0.f, 0.f, 0.f};

    STAGE_A(0, 0); STAGE_B(0, 0);
    STAGE_A(1, 1); STAGE_B(1, 1);
    STAGE_A(2, 2); STAGE_B(2, 2);
    asm volatile("s_waitcnt vmcnt(8)" ::: "memory");
    __builtin_amdgcn_s_barrier();
    __builtin_amdgcn_sched_barrier(0);

#define PH_A(p, DOSTAGE, kt3) do { \
        LDA(0, p); LDA(1, p); LDA(2, p); LDA(3, p); \
        LDB(0, p); LDB(1, p); LDB(2, p); LDB(3, p); \
        if (DOSTAGE) STAGE_A((kt3) & 3, kt3); \
        __builtin_amdgcn_s_setprio(1); \
        _Pragma("unroll") \
        for (int mm = 0; mm < 4; mm++) \
            _Pragma("unroll") \
            for (int nn = 0; nn < 4; nn++) \
                acc[mm][nn] = __builtin_amdgcn_mfma_f32_16x16x32_bf16( \
                    fa[mm], fb[nn], acc[mm][nn], 0, 0, 0); \
        __builtin_amdgcn_s_setprio(0); } while (0)

#define PH_B(p, DOSTAGE, kt3, VMSTR) do { \
        LDA(4, p); LDA(5, p); LDA(6, p); LDA(7, p); \
        if (DOSTAGE) STAGE_B((kt3) & 3, kt3); \
        __builtin_amdgcn_s_setprio(1); \
        _Pragma("unroll") \
        for (int mm = 0; mm < 4; mm++) \
            _Pragma("unroll") \
            for (int nn = 0; nn < 4; nn++) \
                acc[4 + mm][nn] = __builtin_amdgcn_mfma_f32_16x16x32_bf16( \
                    fa[4 + mm], fb[nn], acc[4 + mm][nn], 0, 0, 0); \
        __builtin_amdgcn_s_setprio(0); \
        asm volatile(VMSTR ::: "memory"); \
        __builtin_amdgcn_s_barrier(); \
        __builtin_amdgcn_sched_barrier(0); } while (0)

#pragma unroll 4
    for (int tt = 0; tt < NT - 4; ++tt) {
        const int p = tt & 3;
        PH_A(p, 1, tt + 3);
        PH_B(p, 1, tt + 3, "s_waitcnt vmcnt(8)");
    }
    PH_A(0, 1, 127); PH_B(0, 1, 127, "s_waitcnt vmcnt(8)");
    PH_A(1, 0, 0);   PH_B(1, 0, 0, "s_waitcnt vmcnt(4)");
    PH_A(2, 0, 0);   PH_B(2, 0, 0, "s_waitcnt vmcnt(0)");
    PH_A(3, 0, 0);   PH_B(3, 0, 0, "s_waitcnt vmcnt(0)");

    float bias[4], w4v[4];
#pragma unroll
    for (int n = 0; n < 4; n++) {
        int col = bcol + wn * 64 + n * 16 + l15;
        bias[n] = b3[col];
        w4v[n] = W4[col];
    }
#pragma unroll
    for (int m = 0; m < 8; m++) {
        float pr0 = 0.f, pr1 = 0.f, pr2 = 0.f, pr3 = 0.f;
#pragma unroll
        for (int n = 0; n < 4; n++) {
            pr0 += fmaxf(acc[m][n][0] + bias[n], 0.f) * w4v[n];
            pr1 += fmaxf(acc[m][n][1] + bias[n], 0.f) * w4v[n];
            pr2 += fmaxf(acc[m][n][2] + bias[n], 0.f) * w4v[n];
            pr3 += fmaxf(acc[m][n][3] + bias[n], 0.f) * w4v[n];
        }
#pragma unroll
        for (int mask = 1; mask < 16; mask <<= 1) {
            pr0 += __shfl_xor(pr0, mask, 64);
            pr1 += __shfl_xor(pr1, mask, 64);
            pr2 += __shfl_xor(pr2, mask, 64);
            pr3 += __shfl_xor(pr3, mask, 64);
        }
        if (l15 == 0) {
            int row = brow + wm * 128 + m * 16 + g * 4;
            atomicAdd(&out[row + 0], pr0);
            atomicAdd(&out[row + 1], pr1);
            atomicAdd(&out[row + 2], pr2);
            atomicAdd(&out[row + 3], pr3);
        }
    }
}

// ---------------------------------------------------------------------------
extern "C" void kernel_launch(void* const* d_in, const int* in_sizes, int n_in,
                              void* d_out, int out_size, void* d_ws, size_t ws_size,
                              hipStream_t stream) {
    const float* inputs = (const float*)d_in[0];
    const float* W1 = (const float*)d_in[1];
    const float* b1 = (const float*)d_in[2];
    const float* W2 = (const float*)d_in[3];
    const float* b2 = (const float*)d_in[4];
    const float* imp = (const float*)d_in[5];
    const float* W3 = (const float*)d_in[6];
    const float* b3 = (const float*)d_in[7];
    const float* W4 = (const float*)d_in[8];
    const float* b4 = (const float*)d_in[9];
    float* out = (float*)d_out;

    char* ws = (char*)d_ws;
    const size_t agg_bytes = (size_t)B_ROWS * KDIM * 2;        // 134 MB
    const size_t w3t_bytes = (size_t)H2 * KDIM * 2;            // 8.4 MB
    const size_t w1b_bytes = (size_t)NVARS * 64 * 40 * 2;
    const size_t w2b_bytes = (size_t)NVARS * 64 * 72 * 2;

    __hip_bfloat16* agg = (__hip_bfloat16*)ws;
    __hip_bfloat16* w3t = (__hip_bfloat16*)(ws + agg_bytes);
    short* w1bh = (short*)(ws + agg_bytes + w3t_bytes);
    short* w1bl = (short*)(ws + agg_bytes + w3t_bytes + w1b_bytes);
    short* w2bh = (short*)(ws + agg_bytes + w3t_bytes + 2 * w1b_bytes);
    short* w2bl = (short*)(ws + agg_bytes + w3t_bytes + 2 * w1b_bytes + w2b_bytes);

    hipLaunchKernelGGL(misc_pre_kernel, dim3(1152), dim3(256), 0, stream,
                       W3, b4, W1, W2, w3t, out, w1bh, w1bl, w2bh, w2bl);
    hipLaunchKernelGGL(subnets_mfma_kernel, dim3(NVARS * (B_ROWS / 128)), dim3(256), 0, stream,
                       inputs, b1, b2, imp, w1bh, w1bl, w2bh, w2bl, agg);
    hipLaunchKernelGGL(gemm3_kernel, dim3((B_ROWS / 256) * (H2 / 256)), dim3(512), 0, stream,
                       agg, w3t, b3, W4, out);
}

// Round 8
// 167.234 us; speedup vs baseline: 1.1025x; 1.0718x over previous
//
#include <hip/hip_runtime.h>
#include <hip/hip_bf16.h>
#include <stdint.h>

#define B_ROWS 16384
#define NVARS 64
#define LAG 16
#define H1 64
#define H2 1024
#define KDIM (NVARS * H1)   // 4096

typedef __attribute__((ext_vector_type(8))) short short8;
typedef __attribute__((ext_vector_type(4))) short short4v;
typedef __attribute__((ext_vector_type(4))) float f32x4;

typedef __attribute__((address_space(3))) uint8_t lds_u8;
typedef const __attribute__((address_space(1))) uint8_t glob_u8;

__device__ __forceinline__ void gload_lds16(const void* g, void* l) {
    __builtin_amdgcn_global_load_lds((glob_u8*)g, (lds_u8*)l, 16, 0, 0);
}

__device__ __forceinline__ short f2bf_s(float x) {
    __hip_bfloat16 h = __float2bfloat16(x);
    return *(short*)&h;
}
__device__ __forceinline__ float bf_s2f(short s) {
    __hip_bfloat16 h = *(__hip_bfloat16*)&s;
    return __bfloat162float(h);
}

// ---------------------------------------------------------------------------
// Kernel 1 (run-once misc, one dispatch):
//   [0,1024)    : W3 [4096][1024] f32 -> W3T [1024][4096] bf16 (LDS transpose)
//   [1024,1088) : out[i] = b4[0]
//   [1088,1152) : per-var W1/W2 -> hi/lo B-operand tiles (global writes)
// ---------------------------------------------------------------------------
__global__ __launch_bounds__(256) void misc_pre_kernel(
    const float* __restrict__ w3, const float* __restrict__ b4,
    const float* __restrict__ W1, const float* __restrict__ W2,
    __hip_bfloat16* __restrict__ w3t, float* __restrict__ out,
    short* __restrict__ w1bh, short* __restrict__ w1bl,
    short* __restrict__ w2bh, short* __restrict__ w2bl) {
    __shared__ float tile[64][65];
    const int bid = blockIdx.x;
    const int t = threadIdx.x;

    if (bid < 1024) {
        const int k0 = (bid >> 4) * 64;
        const int n0 = (bid & 15) * 64;
        const int c = t & 63, r0 = t >> 6;
#pragma unroll
        for (int i = 0; i < 16; i++) {
            int r = r0 + i * 4;
            tile[r][c] = w3[(size_t)(k0 + r) * H2 + n0 + c];
        }
        __syncthreads();
#pragma unroll
        for (int i = 0; i < 16; i++) {
            int nr = r0 + i * 4;
            w3t[(size_t)(n0 + nr) * KDIM + k0 + c] = __float2bfloat16(tile[c][nr]);
        }
        return;
    }
    if (bid < 1088) {
        out[(bid - 1024) * 256 + t] = b4[0];
        return;
    }

    const int v = bid - 1088;
    for (int idx = t; idx < 64 * 32; idx += 256) {
        int col = idx >> 5, k = idx & 31;
        float wv = W1[((size_t)v * LAG + (k & 15)) * H1 + col];
        short hi = f2bf_s(wv);
        w1bh[((size_t)v * 64 + col) * 40 + k] = hi;
        w1bl[((size_t)v * 64 + col) * 40 + k] = (k < 16) ? f2bf_s(wv - bf_s2f(hi)) : (short)0;
    }
    for (int idx = t; idx < 64 * 64; idx += 256) {
        int col = idx >> 6, k = idx & 63;
        float wv = W2[((size_t)v * H1 + k) * H1 + col];
        short hi = f2bf_s(wv);
        w2bh[((size_t)v * 64 + col) * 72 + k] = hi;
        w2bl[((size_t)v * 64 + col) * 72 + k] = f2bf_s(wv - bf_s2f(hi));
    }
}

// ---------------------------------------------------------------------------
// Kernel 2: per-variable 2-layer subnet via split-bf16 MFMA.
// r8 slimming: h1 kept as plain bf16 (h-lo term dropped in layer 2) ->
//   - no per-thread hi/lo split of H (saves ~100 VALU + 32 LDS stores/thread)
//   - layer 2 = 4 MFMAs/tile (h_hi*W_hi + h_hi*W_lo), was 6
//   - LDS 52 -> 38.9 KB => 4 blocks/CU (16 waves), was 3
// x and W1/W2 hi/lo splits unchanged (layer-1 still full split precision).
// ---------------------------------------------------------------------------
__global__ __launch_bounds__(256) void subnets_mfma_kernel(
    const float* __restrict__ inputs, const float* __restrict__ b1g,
    const float* __restrict__ b2g, const float* __restrict__ impg,
    const short* __restrict__ w1bh_g, const short* __restrict__ w1bl_g,
    const short* __restrict__ w2bh_g, const short* __restrict__ w2bl_g,
    __hip_bfloat16* __restrict__ agg) {
    const int v = blockIdx.x >> 7;
    const int b0 = (blockIdx.x & 127) * 128;
    const int t = threadIdx.x;
    const int lane = t & 63, wv = t >> 6;
    const int l15 = lane & 15, g = lane >> 4;

    // LDS map: [0,20480) = xs[128][40] (10240) + w1bh[64][40] (5120) +
    //          w1bl (5120); post-L1 the same region holds Hs[128][72] (18432).
    //          [20480,29696) w2bh[64][72]; [29696,38912) w2bl.
    __shared__ __align__(16) char smem[38912];
    short* xsS   = (short*)smem;
    short* w1bhS = (short*)(smem + 10240);
    short* w1blS = (short*)(smem + 15360);
    short* Hs    = (short*)smem;
    short* w2bhS = (short*)(smem + 20480);
    short* w2blS = (short*)(smem + 29696);

    for (int c = t; c < 320; c += 256) {
        gload_lds16(w1bh_g + (size_t)v * 2560 + c * 8, (char*)w1bhS + c * 16);
        gload_lds16(w1bl_g + (size_t)v * 2560 + c * 8, (char*)w1blS + c * 16);
    }
    for (int c = t; c < 576; c += 256) {
        gload_lds16(w2bh_g + (size_t)v * 4608 + c * 8, (char*)w2bhS + c * 16);
        gload_lds16(w2bl_g + (size_t)v * 4608 + c * 8, (char*)w2blS + c * 16);
    }
#pragma unroll
    for (int i = 0; i < 2; i++) {
        int idx = t + i * 256;
        int row = idx >> 2, seg = idx & 3;
        float4 x4 = *(const float4*)(inputs + (size_t)(b0 + row) * (NVARS * LAG) + v * LAG + seg * 4);
        const float* xp = (const float*)&x4;
        short4v hv, lv;
#pragma unroll
        for (int j = 0; j < 4; j++) {
            short hi = f2bf_s(xp[j]);
            hv[j] = hi;
            lv[j] = f2bf_s(xp[j] - bf_s2f(hi));
        }
        *(short4v*)&xsS[row * 40 + seg * 4] = hv;
        *(short4v*)&xsS[row * 40 + 16 + seg * 4] = lv;
    }
    __syncthreads();

    // layer 1 (full split precision, unchanged)
    short8 a1[2], b1hF[4], b1lF[4];
#pragma unroll
    for (int mt = 0; mt < 2; mt++)
        a1[mt] = *(const short8*)&xsS[(wv * 32 + mt * 16 + l15) * 40 + g * 8];
#pragma unroll
    for (int nt = 0; nt < 4; nt++) {
        b1hF[nt] = *(const short8*)&w1bhS[(nt * 16 + l15) * 40 + g * 8];
        b1lF[nt] = *(const short8*)&w1blS[(nt * 16 + l15) * 40 + g * 8];
    }
    f32x4 acc1[2][4];
#pragma unroll
    for (int mt = 0; mt < 2; mt++)
#pragma unroll
        for (int nt = 0; nt < 4; nt++) {
            acc1[mt][nt] = (f32x4){0.f, 0.f, 0.f, 0.f};
            acc1[mt][nt] = __builtin_amdgcn_mfma_f32_16x16x32_bf16(a1[mt], b1hF[nt], acc1[mt][nt], 0, 0, 0);
            acc1[mt][nt] = __builtin_amdgcn_mfma_f32_16x16x32_bf16(a1[mt], b1lF[nt], acc1[mt][nt], 0, 0, 0);
        }
    __syncthreads();

    // relu -> H as plain bf16 [128][72]
#pragma unroll
    for (int mt = 0; mt < 2; mt++)
#pragma unroll
        for (int nt = 0; nt < 4; nt++) {
            int col = nt * 16 + l15;
            float bias = b1g[v * H1 + col];
#pragma unroll
            for (int r = 0; r < 4; r++) {
                float h = fmaxf(acc1[mt][nt][r] + bias, 0.f);
                int row = wv * 32 + mt * 16 + g * 4 + r;
                Hs[row * 72 + col] = f2bf_s(h);
            }
        }
    __syncthreads();

    // layer 2: acc2 = h_bf16 * (W2_hi + W2_lo)
    short8 a2[2][2], b2hF[4][2], b2lF[4][2];
#pragma unroll
    for (int mt = 0; mt < 2; mt++)
#pragma unroll
        for (int kc = 0; kc < 2; kc++)
            a2[mt][kc] = *(const short8*)&Hs[(wv * 32 + mt * 16 + l15) * 72 + kc * 32 + g * 8];
#pragma unroll
    for (int nt = 0; nt < 4; nt++)
#pragma unroll
        for (int kc = 0; kc < 2; kc++) {
            b2hF[nt][kc] = *(const short8*)&w2bhS[(nt * 16 + l15) * 72 + kc * 32 + g * 8];
            b2lF[nt][kc] = *(const short8*)&w2blS[(nt * 16 + l15) * 72 + kc * 32 + g * 8];
        }
    f32x4 acc2[2][4];
#pragma unroll
    for (int mt = 0; mt < 2; mt++)
#pragma unroll
        for (int nt = 0; nt < 4; nt++) {
            f32x4 a = (f32x4){0.f, 0.f, 0.f, 0.f};
            a = __builtin_amdgcn_mfma_f32_16x16x32_bf16(a2[mt][0], b2hF[nt][0], a, 0, 0, 0);
            a = __builtin_amdgcn_mfma_f32_16x16x32_bf16(a2[mt][1], b2hF[nt][1], a, 0, 0, 0);
            a = __builtin_amdgcn_mfma_f32_16x16x32_bf16(a2[mt][0], b2lF[nt][0], a, 0, 0, 0);
            a = __builtin_amdgcn_mfma_f32_16x16x32_bf16(a2[mt][1], b2lF[nt][1], a, 0, 0, 0);
            acc2[mt][nt] = a;
        }

    const float impv = impg[v];
#pragma unroll
    for (int mt = 0; mt < 2; mt++)
#pragma unroll
        for (int nt = 0; nt < 4; nt++) {
            int col = nt * 16 + l15;
            float bias = b2g[v * H1 + col];
#pragma unroll
            for (int r = 0; r < 4; r++) {
                float o = fmaxf(acc2[mt][nt][r] + bias, 0.f) * impv;
                int row = b0 + wv * 32 + mt * 16 + g * 4 + r;
                agg[(size_t)row * KDIM + v * H1 + col] = __float2bfloat16(o);
            }
        }
}

// ---------------------------------------------------------------------------
// Kernel 3: relu(agg @ W3 + b3) . W4 -> atomicAdd into out.
// r6/r7-validated single-barrier schedule: 256x256 tile, BK=32, 8 waves,
// 4 LDS buffer pairs, stage tt+3 during tt, 1 barrier + 1 vmcnt(8) per tile.
// ---------------------------------------------------------------------------
#define NT 128   // K-tiles of 32

__global__ __launch_bounds__(512, 2) void gemm3_kernel(
    const __hip_bfloat16* __restrict__ agg,   // [16384][4096]
    const __hip_bfloat16* __restrict__ w3t,   // [1024][4096]
    const float* __restrict__ b3, const float* __restrict__ W4,
    float* __restrict__ out) {
    const int bid = ((blockIdx.x & 7) << 5) + (blockIdx.x >> 3);
    const int brow = (bid >> 2) * 256;
    const int bcol = (bid & 3) * 256;
    const int t = threadIdx.x;
    const int lane = t & 63;
    const int wid = t >> 6;
    const int wm = wid >> 2, wn = wid & 3;
    const int l15 = lane & 15, g = lane >> 4;

    __shared__ __align__(16) char smem[131072];

    const int c0 = t, c1 = t + 512;
    const int r0 = c0 >> 2, r1 = c1 >> 2;
    const int col0 = ((c0 & 3) * 8) ^ ((r0 & 8) ? 16 : 0);
    const int col1 = ((c1 & 3) * 8) ^ ((r1 & 8) ? 16 : 0);
    const __hip_bfloat16* aS0 = agg + (size_t)(brow + r0) * KDIM + col0;
    const __hip_bfloat16* aS1 = agg + (size_t)(brow + r1) * KDIM + col1;
    const __hip_bfloat16* bS0 = w3t + (size_t)(bcol + r0) * KDIM + col0;
    const __hip_bfloat16* bS1 = w3t + (size_t)(bcol + r1) * KDIM + col1;

#define STAGE_A(p, kt) do { \
        gload_lds16(aS0 + (kt) * 32, smem + (p) * 32768 + c0 * 16); \
        gload_lds16(aS1 + (kt) * 32, smem + (p) * 32768 + c1 * 16); } while (0)
#define STAGE_B(p, kt) do { \
        gload_lds16(bS0 + (kt) * 32, smem + (p) * 32768 + 16384 + c0 * 16); \
        gload_lds16(bS1 + (kt) * 32, smem + (p) * 32768 + 16384 + c1 * 16); } while (0)

    const int coff = (g * 16) ^ ((l15 & 8) ? 32 : 0);
    const int aBase = (wm * 128 + l15) * 64 + coff;
    const int bBase = 16384 + (wn * 64 + l15) * 64 + coff;

#define LDA(i, p) fa[i] = *(const short8*)(smem + (p) * 32768 + aBase + (i) * 1024)
#define LDB(i, p) fb[i] = *(const short8*)(smem + (p) * 32768 + bBase + (i) * 1024)

    short8 fa[8], fb[4];
    f32x4 acc[8][4];
#pragma unroll
    for (int m = 0; m < 8; m++)
#pragma unroll
        for (int n = 0; n < 4; n++) acc[m][n] = (f32x4){0.f, 0.f, 0.f, 0.f};

    STAGE_A(0, 0); STAGE_B(0, 0);
    STAGE_A(1, 1); STAGE_B(1, 1);
    STAGE_A(2, 2); STAGE_B(2, 2);
    asm volatile("s_waitcnt vmcnt(8)" ::: "memory");
    __builtin_amdgcn_s_barrier();
    __builtin_amdgcn_sched_barrier(0);

#define PH_A(p, DOSTAGE, kt3) do { \
        LDA(0, p); LDA(1, p); LDA(2, p); LDA(3, p); \
        LDB(0, p); LDB(1, p); LDB(2, p); LDB(3, p); \
        if (DOSTAGE) STAGE_A((kt3) & 3, kt3); \
        __builtin_amdgcn_s_setprio(1); \
        _Pragma("unroll") \
        for (int mm = 0; mm < 4; mm++) \
            _Pragma("unroll") \
            for (int nn = 0; nn < 4; nn++) \
                acc[mm][nn] = __builtin_amdgcn_mfma_f32_16x16x32_bf16( \
                    fa[mm], fb[nn], acc[mm][nn], 0, 0, 0); \
        __builtin_amdgcn_s_setprio(0); } while (0)

#define PH_B(p, DOSTAGE, kt3, VMSTR) do { \
        LDA(4, p); LDA(5, p); LDA(6, p); LDA(7, p); \
        if (DOSTAGE) STAGE_B((kt3) & 3, kt3); \
        __builtin_amdgcn_s_setprio(1); \
        _Pragma("unroll") \
        for (int mm = 0; mm < 4; mm++) \
            _Pragma("unroll") \
            for (int nn = 0; nn < 4; nn++) \
                acc[4 + mm][nn] = __builtin_amdgcn_mfma_f32_16x16x32_bf16( \
                    fa[4 + mm], fb[nn], acc[4 + mm][nn], 0, 0, 0); \
        __builtin_amdgcn_s_setprio(0); \
        asm volatile(VMSTR ::: "memory"); \
        __builtin_amdgcn_s_barrier(); \
        __builtin_amdgcn_sched_barrier(0); } while (0)

#pragma unroll 4
    for (int tt = 0; tt < NT - 4; ++tt) {
        const int p = tt & 3;
        PH_A(p, 1, tt + 3);
        PH_B(p, 1, tt + 3, "s_waitcnt vmcnt(8)");
    }
    PH_A(0, 1, 127); PH_B(0, 1, 127, "s_waitcnt vmcnt(8)");
    PH_A(1, 0, 0);   PH_B(1, 0, 0, "s_waitcnt vmcnt(4)");
    PH_A(2, 0, 0);   PH_B(2, 0, 0, "s_waitcnt vmcnt(0)");
    PH_A(3, 0, 0);   PH_B(3, 0, 0, "s_waitcnt vmcnt(0)");

    float bias[4], w4v[4];
#pragma unroll
    for (int n = 0; n < 4; n++) {
        int col = bcol + wn * 64 + n * 16 + l15;
        bias[n] = b3[col];
        w4v[n] = W4[col];
    }
#pragma unroll
    for (int m = 0; m < 8; m++) {
        float pr0 = 0.f, pr1 = 0.f, pr2 = 0.f, pr3 = 0.f;
#pragma unroll
        for (int n = 0; n < 4; n++) {
            pr0 += fmaxf(acc[m][n][0] + bias[n], 0.f) * w4v[n];
            pr1 += fmaxf(acc[m][n][1] + bias[n], 0.f) * w4v[n];
            pr2 += fmaxf(acc[m][n][2] + bias[n], 0.f) * w4v[n];
            pr3 += fmaxf(acc[m][n][3] + bias[n], 0.f) * w4v[n];
        }
#pragma unroll
        for (int mask = 1; mask < 16; mask <<= 1) {
            pr0 += __shfl_xor(pr0, mask, 64);
            pr1 += __shfl_xor(pr1, mask, 64);
            pr2 += __shfl_xor(pr2, mask, 64);
            pr3 += __shfl_xor(pr3, mask, 64);
        }
        if (l15 == 0) {
            int row = brow + wm * 128 + m * 16 + g * 4;
            atomicAdd(&out[row + 0], pr0);
            atomicAdd(&out[row + 1], pr1);
            atomicAdd(&out[row + 2], pr2);
            atomicAdd(&out[row + 3], pr3);
        }
    }
}

// ---------------------------------------------------------------------------
extern "C" void kernel_launch(void* const* d_in, const int* in_sizes, int n_in,
                              void* d_out, int out_size, void* d_ws, size_t ws_size,
                              hipStream_t stream) {
    const float* inputs = (const float*)d_in[0];
    const float* W1 = (const float*)d_in[1];
    const float* b1 = (const float*)d_in[2];
    const float* W2 = (const float*)d_in[3];
    const float* b2 = (const float*)d_in[4];
    const float* imp = (const float*)d_in[5];
    const float* W3 = (const float*)d_in[6];
    const float* b3 = (const float*)d_in[7];
    const float* W4 = (const float*)d_in[8];
    const float* b4 = (const float*)d_in[9];
    float* out = (float*)d_out;

    char* ws = (char*)d_ws;
    const size_t agg_bytes = (size_t)B_ROWS * KDIM * 2;        // 134 MB
    const size_t w3t_bytes = (size_t)H2 * KDIM * 2;            // 8.4 MB
    const size_t w1b_bytes = (size_t)NVARS * 64 * 40 * 2;
    const size_t w2b_bytes = (size_t)NVARS * 64 * 72 * 2;

    __hip_bfloat16* agg = (__hip_bfloat16*)ws;
    __hip_bfloat16* w3t = (__hip_bfloat16*)(ws + agg_bytes);
    short* w1bh = (short*)(ws + agg_bytes + w3t_bytes);
    short* w1bl = (short*)(ws + agg_bytes + w3t_bytes + w1b_bytes);
    short* w2bh = (short*)(ws + agg_bytes + w3t_bytes + 2 * w1b_bytes);
    short* w2bl = (short*)(ws + agg_bytes + w3t_bytes + 2 * w1b_bytes + w2b_bytes);

    hipLaunchKernelGGL(misc_pre_kernel, dim3(1152), dim3(256), 0, stream,
                       W3, b4, W1, W2, w3t, out, w1bh, w1bl, w2bh, w2bl);
    hipLaunchKernelGGL(subnets_mfma_kernel, dim3(NVARS * (B_ROWS / 128)), dim3(256), 0, stream,
                       inputs, b1, b2, imp, w1bh, w1bl, w2bh, w2bl, agg);
    hipLaunchKernelGGL(gemm3_kernel, dim3((B_ROWS / 256) * (H2 / 256)), dim3(512), 0, stream,
                       agg, w3t, b3, W4, out);
}